// Round 5
// baseline (110.699 us; speedup 1.0000x reference)
//
#include <hip/hip_runtime.h>
#include <hip/hip_bf16.h>

typedef float f32x4 __attribute__((ext_vector_type(4)));
typedef short bf16x8 __attribute__((ext_vector_type(8)));
typedef unsigned short u16;

#define NTOK 768
#define DMOD 512
#define NH   16
#define DH   32
#define CZd  128
#define NN   (768*768)

static __device__ __forceinline__ u16 f2bf(float f) {
  __hip_bfloat16 h = __float2bfloat16(f);
  return __builtin_bit_cast(u16, h);
}
static __device__ __forceinline__ float bf2f(u16 u) {
  unsigned int x = ((unsigned int)u) << 16;
  return __builtin_bit_cast(float, x);
}

// ---------------------------------------------------------------------------
// K0 "prep": ONE launch; z-stream blocks first, cvt/LN ride along in the tail.
//   blocks [0,9216)      : z path: LN(z) -> @z_w -> bias bf16 [i][h][j]
//   blocks [9216,10496)  : convert 5 weight mats f32 [k][n] -> bf16 [n][k]
//   blocks [10496,10688) : LayerNorm(s) -> bf16, 4 rows per block
__global__ __launch_bounds__(256) void prep_kernel(
    const float* __restrict__ s, const float* __restrict__ nsw, const float* __restrict__ nsb,
    const float* __restrict__ qw, const float* __restrict__ kw, const float* __restrict__ vw,
    const float* __restrict__ gw, const float* __restrict__ ow,
    const float* __restrict__ z, const float* __restrict__ znw, const float* __restrict__ znb,
    const float* __restrict__ zwp,
    u16* __restrict__ wbf, u16* __restrict__ snb, u16* __restrict__ biasb) {
  __shared__ char SM[17408];
  int bid = blockIdx.x;
  int t = threadIdx.x;

  if (bid >= 9216) {
    if (bid < 10496) {         // ---- weight convert+transpose ----
      float (*tbuf)[33] = (float(*)[33])SM;
      int wb = bid - 9216;
      int seg = wb / 256;
      int tile = wb % 256;
      int k0 = (tile / 16) * 32;
      int n0 = (tile % 16) * 32;
      const float* src = seg==0?qw: seg==1?kw: seg==2?vw: seg==3?gw: ow;
      u16* out = wbf + (size_t)seg * (DMOD*DMOD);
      int tr  = t / 8;
      int tc4 = (t % 8) * 4;
      float4 v = *(const float4*)(src + (size_t)(k0+tr)*DMOD + n0 + tc4);
      tbuf[tr][tc4+0]=v.x; tbuf[tr][tc4+1]=v.y; tbuf[tr][tc4+2]=v.z; tbuf[tr][tc4+3]=v.w;
      __syncthreads();
      int nr  = t / 8;
      int kc4 = (t % 8) * 4;
      ushort4 o;
      o.x = f2bf(tbuf[kc4+0][nr]);
      o.y = f2bf(tbuf[kc4+1][nr]);
      o.z = f2bf(tbuf[kc4+2][nr]);
      o.w = f2bf(tbuf[kc4+3][nr]);
      *(ushort4*)(out + (size_t)(n0+nr)*DMOD + k0 + kc4) = o;
    } else {                   // ---- LayerNorm(s), 4 rows/block ----
      int i = (bid - 10496)*4 + (t >> 6);
      int lane = t & 63;
      const float* row = s + (size_t)i*DMOD + lane*8;
      float4 a0 = *(const float4*)(row);
      float4 a1 = *(const float4*)(row + 4);
      float sum = a0.x+a0.y+a0.z+a0.w + a1.x+a1.y+a1.z+a1.w;
      float sq  = a0.x*a0.x+a0.y*a0.y+a0.z*a0.z+a0.w*a0.w
                + a1.x*a1.x+a1.y*a1.y+a1.z*a1.z+a1.w*a1.w;
      #pragma unroll
      for (int mk=1; mk<64; mk<<=1) { sum += __shfl_xor(sum,mk); sq += __shfl_xor(sq,mk); }
      float mu  = sum * (1.f/512.f);
      float var = sq  * (1.f/512.f) - mu*mu;
      float rs  = rsqrtf(var + 1e-5f);
      float4 w0 = *(const float4*)(nsw + lane*8);
      float4 w1 = *(const float4*)(nsw + lane*8 + 4);
      float4 b0 = *(const float4*)(nsb + lane*8);
      float4 b1 = *(const float4*)(nsb + lane*8 + 4);
      bf16x8 o;
      o[0]=(short)f2bf((a0.x-mu)*rs*w0.x+b0.x);
      o[1]=(short)f2bf((a0.y-mu)*rs*w0.y+b0.y);
      o[2]=(short)f2bf((a0.z-mu)*rs*w0.z+b0.z);
      o[3]=(short)f2bf((a0.w-mu)*rs*w0.w+b0.w);
      o[4]=(short)f2bf((a1.x-mu)*rs*w1.x+b1.x);
      o[5]=(short)f2bf((a1.y-mu)*rs*w1.y+b1.y);
      o[6]=(short)f2bf((a1.z-mu)*rs*w1.z+b1.z);
      o[7]=(short)f2bf((a1.w-mu)*rs*w1.w+b1.w);
      *(bf16x8*)(snb + (size_t)i*DMOD + lane*8) = o;
    }
    return;
  }

  // ---- z path (blocks [0,9216)) ----
  u16* zt = (u16*)SM;          // 64 rows x pitch 136 bf16
  int i = bid / 12, j0 = (bid % 12) * 64;
  int lane = t & 63, wv = t >> 6;
  int c16 = lane & 15, c4 = lane >> 4;
  int rsub = lane >> 3;          // 0..7 : row within wave's half-group
  int ch0  = (lane & 7) * 16;    // first channel (float idx)
  const float* ztile = z + ((size_t)i*NTOK + j0)*CZd;
  float4 xv[2][4];
  #pragma unroll
  for (int g=0; g<2; g++) {
    const float* rp = ztile + (size_t)(wv*16 + g*8 + rsub)*CZd + ch0;
    xv[g][0] = *(const float4*)(rp);
    xv[g][1] = *(const float4*)(rp+4);
    xv[g][2] = *(const float4*)(rp+8);
    xv[g][3] = *(const float4*)(rp+12);
  }
  // z_w fragments: 32 scalar L2 loads (hidden under the z stream)
  bf16x8 bfr[4];
  #pragma unroll
  for (int ks=0; ks<4; ks++) {
    #pragma unroll
    for (int jj=0; jj<8; jj++)
      bfr[ks][jj] = (short)f2bf(zwp[(ks*32 + c4*8 + jj)*16 + c16]);
  }
  float4 w4[4], b4[4];
  #pragma unroll
  for (int q=0; q<4; q++) {
    w4[q] = *(const float4*)(znw + ch0 + q*4);
    b4[q] = *(const float4*)(znb + ch0 + q*4);
  }
  #pragma unroll
  for (int g=0; g<2; g++) {
    float sum=0.f, sq=0.f;
    #pragma unroll
    for (int q=0; q<4; q++) {
      float4 v = xv[g][q];
      sum += v.x+v.y+v.z+v.w;
      sq  += v.x*v.x+v.y*v.y+v.z*v.z+v.w*v.w;
    }
    sum += __shfl_xor(sum,1); sq += __shfl_xor(sq,1);
    sum += __shfl_xor(sum,2); sq += __shfl_xor(sq,2);
    sum += __shfl_xor(sum,4); sq += __shfl_xor(sq,4);
    float mu = sum*(1.f/128.f);
    float rs = rsqrtf(sq*(1.f/128.f) - mu*mu + 1e-5f);
    int row = wv*16 + g*8 + rsub;
    #pragma unroll
    for (int hh=0; hh<2; hh++) {
      bf16x8 o;
      #pragma unroll
      for (int q=0; q<2; q++) {
        float4 v = xv[g][hh*2+q];
        float4 w = w4[hh*2+q], b = b4[hh*2+q];
        o[q*4+0]=(short)f2bf((v.x-mu)*rs*w.x+b.x);
        o[q*4+1]=(short)f2bf((v.y-mu)*rs*w.y+b.y);
        o[q*4+2]=(short)f2bf((v.z-mu)*rs*w.z+b.z);
        o[q*4+3]=(short)f2bf((v.w-mu)*rs*w.w+b.w);
      }
      *(bf16x8*)(zt + row*136 + ch0 + hh*8) = o;
    }
  }
  __syncthreads();
  f32x4 acc = {0,0,0,0};
  #pragma unroll
  for (int ks=0; ks<4; ks++) {
    bf16x8 af = *(const bf16x8*)(zt + (wv*16 + c16)*136 + ks*32 + c4*8);
    acc = __builtin_amdgcn_mfma_f32_16x16x32_bf16(af, bfr[ks], acc, 0,0,0);
  }
  int jl = j0 + wv*16 + c4*4;
  u16* bp = biasb + ((size_t)i*NH + c16)*NTOK + jl;
  ushort4 st;
  st.x = f2bf(acc[0]); st.y = f2bf(acc[1]); st.z = f2bf(acc[2]); st.w = f2bf(acc[3]);
  *(ushort4*)bp = st;
}

// ---------------------------------------------------------------------------
// K2: fused Q/K/V/G projections, NO LDS (operands L2-resident), no barriers.
//     grid = 24 (M/32) * 32 (4 mats * 512/64) = 768 blocks of 256.
__global__ __launch_bounds__(256) void qkvg_kernel(
    const u16* __restrict__ sn, const u16* __restrict__ wts, const float* __restrict__ qb,
    u16* __restrict__ qo, u16* __restrict__ ko, u16* __restrict__ vTo, float* __restrict__ go) {
  int bid = blockIdx.x;
  int mb = bid % 24, nb = bid / 24;
  int wsel = nb >> 3, n0 = (nb & 7) * 64, m0 = mb * 32;
  const u16* wt = wts + (size_t)wsel * (DMOD*DMOD);
  int t = threadIdx.x, lane = t & 63, wv = t >> 6;
  int wm = (wv >> 1) * 16, wn = (wv & 1) * 32;
  int c16 = lane & 15, c4 = lane >> 4;
  const u16* arow  = sn + (size_t)(m0 + wm + c16)*DMOD + c4*8;
  const u16* brow0 = wt + (size_t)(n0 + wn + c16)*DMOD + c4*8;
  const u16* brow1 = wt + (size_t)(n0 + wn + 16 + c16)*DMOD + c4*8;
  f32x4 acc0={0,0,0,0}, acc1={0,0,0,0};
  #pragma unroll 4
  for (int k0 = 0; k0 < DMOD; k0 += 32) {
    bf16x8 a  = *(const bf16x8*)(arow  + k0);
    bf16x8 b0 = *(const bf16x8*)(brow0 + k0);
    bf16x8 b1 = *(const bf16x8*)(brow1 + k0);
    acc0 = __builtin_amdgcn_mfma_f32_16x16x32_bf16(a,b0,acc0,0,0,0);
    acc1 = __builtin_amdgcn_mfma_f32_16x16x32_bf16(a,b1,acc1,0,0,0);
  }
  int r0 = c4*4;
  #pragma unroll
  for (int bn=0; bn<2; bn++) {
    f32x4 acc = bn==0?acc0:acc1;
    #pragma unroll
    for (int rr=0; rr<4; rr++) {
      int i = m0 + wm + r0 + rr;
      int n = n0 + wn + bn*16 + c16;
      float val = acc[rr];
      if (wsel == 0)      { val += qb[n]; qo[(size_t)i*DMOD + n] = f2bf(val); }
      else if (wsel == 1) { ko[(size_t)i*DMOD + n] = f2bf(val); }
      else if (wsel == 2) { vTo[(size_t)n*NTOK + i] = f2bf(val); }
      else                { go[(size_t)i*DMOD + n] = 1.f/(1.f + expf(-val)); }
    }
  }
}

// ---------------------------------------------------------------------------
// K3: flash attention. Block = (head, 16-row i-tile), 4 waves split j 4 ways;
//     exact partial-sum combine (no max subtraction). Bias/K/V direct from
//     global (L2-resident). Only LDS: P transpose + combine buffers.
//     grid = 768 blocks of 256.
__global__ __launch_bounds__(256) void attn_kernel(
    const u16* __restrict__ qm, const u16* __restrict__ km, const u16* __restrict__ vTm,
    const u16* __restrict__ bias, const float* __restrict__ gm, u16* __restrict__ og) {
  __shared__ u16 Pt[4][16*72];
  __shared__ float OS[4][16][33];
  __shared__ float LS[4][16];
  int h  = blockIdx.x & 15;
  int i0 = (blockIdx.x >> 4) * 16;
  int t = threadIdx.x, lane = t & 63, wv = t >> 6;
  int c16 = lane & 15, c4 = lane >> 4, r0 = c4 * 4;
  bf16x8 qf = *(const bf16x8*)(qm + (size_t)(i0 + c16)*DMOD + h*DH + c4*8);
  f32x4 o0 = {0,0,0,0}, o1 = {0,0,0,0};
  float ls[4] = {0.f,0.f,0.f,0.f};
  const float scale = 0.17677669529663687f;  // 32^-0.5
  const u16* bbase = bias + ((size_t)i0*NH + h)*NTOK;   // [i][h][j]
  u16* pt = &Pt[wv][0];
  for (int jj = 0; jj < 3; jj++) {
    int j0 = wv*192 + jj*64;
    bf16x8 kf0 = *(const bf16x8*)(km + (size_t)(j0 +  0 + c16)*DMOD + h*DH + c4*8);
    bf16x8 kf1 = *(const bf16x8*)(km + (size_t)(j0 + 16 + c16)*DMOD + h*DH + c4*8);
    bf16x8 kf2 = *(const bf16x8*)(km + (size_t)(j0 + 32 + c16)*DMOD + h*DH + c4*8);
    bf16x8 kf3 = *(const bf16x8*)(km + (size_t)(j0 + 48 + c16)*DMOD + h*DH + c4*8);
    f32x4 zz = {0,0,0,0};
    f32x4 s0 = __builtin_amdgcn_mfma_f32_16x16x32_bf16(qf,kf0,zz,0,0,0);
    f32x4 s1 = __builtin_amdgcn_mfma_f32_16x16x32_bf16(qf,kf1,zz,0,0,0);
    f32x4 s2 = __builtin_amdgcn_mfma_f32_16x16x32_bf16(qf,kf2,zz,0,0,0);
    f32x4 s3 = __builtin_amdgcn_mfma_f32_16x16x32_bf16(qf,kf3,zz,0,0,0);
    #pragma unroll
    for (int rr=0; rr<4; rr++) {
      const u16* bp = bbase + (size_t)(r0+rr)*(NH*NTOK) + j0 + c16;
      int row = (r0 + rr) * 72;
      float p0 = __expf(s0[rr]*scale + bf2f(bp[ 0]));
      float p1 = __expf(s1[rr]*scale + bf2f(bp[16]));
      float p2 = __expf(s2[rr]*scale + bf2f(bp[32]));
      float p3 = __expf(s3[rr]*scale + bf2f(bp[48]));
      ls[rr] += p0 + p1 + p2 + p3;
      pt[row + 0*16 + c16] = f2bf(p0);
      pt[row + 1*16 + c16] = f2bf(p1);
      pt[row + 2*16 + c16] = f2bf(p2);
      pt[row + 3*16 + c16] = f2bf(p3);
    }
    #pragma unroll
    for (int ks=0; ks<2; ks++) {
      bf16x8 pf = *(const bf16x8*)(pt + c16*72 + ks*32 + c4*8);
      bf16x8 v0 = *(const bf16x8*)(vTm + (size_t)(h*DH + c16)*NTOK      + j0 + ks*32 + c4*8);
      bf16x8 v1 = *(const bf16x8*)(vTm + (size_t)(h*DH + 16 + c16)*NTOK + j0 + ks*32 + c4*8);
      o0 = __builtin_amdgcn_mfma_f32_16x16x32_bf16(pf, v0, o0, 0,0,0);
      o1 = __builtin_amdgcn_mfma_f32_16x16x32_bf16(pf, v1, o1, 0,0,0);
    }
  }
  #pragma unroll
  for (int rr=0; rr<4; rr++) {
    float l = ls[rr];
    l += __shfl_xor(l,1); l += __shfl_xor(l,2); l += __shfl_xor(l,4); l += __shfl_xor(l,8);
    OS[wv][r0+rr][c16]      = o0[rr];
    OS[wv][r0+rr][16 + c16] = o1[rr];
    if (c16 == 0) LS[wv][r0+rr] = l;
  }
  __syncthreads();
  #pragma unroll
  for (int u=0; u<2; u++) {
    int idx = t + u*256;
    int row = idx >> 5, d = idx & 31;
    float osum = OS[0][row][d] + OS[1][row][d] + OS[2][row][d] + OS[3][row][d];
    float lsum = LS[0][row] + LS[1][row] + LS[2][row] + LS[3][row];
    int i = i0 + row;
    float g = gm[(size_t)i*DMOD + h*DH + d];
    og[(size_t)i*DMOD + h*DH + d] = f2bf(osum/lsum*g);
  }
}

// ---------------------------------------------------------------------------
// K4: out = og @ o_w, NO LDS (both operands L2-resident), 32x64 tiles.
//     grid = 24*8 = 192 blocks of 256.
__global__ __launch_bounds__(256) void out_kernel(
    const u16* __restrict__ og, const u16* __restrict__ owT, float* __restrict__ out) {
  int bid = blockIdx.x;
  int mb = bid % 24, nb = bid / 24;
  int m0 = mb*32, n0 = nb*64;
  int t = threadIdx.x, lane = t & 63, wv = t >> 6;
  int wm = (wv >> 1) * 16, wn = (wv & 1) * 32;
  int c16 = lane & 15, c4 = lane >> 4;
  const u16* arow  = og  + (size_t)(m0 + wm + c16)*DMOD + c4*8;
  const u16* brow0 = owT + (size_t)(n0 + wn + c16)*DMOD + c4*8;
  const u16* brow1 = owT + (size_t)(n0 + wn + 16 + c16)*DMOD + c4*8;
  f32x4 acc0={0,0,0,0}, acc1={0,0,0,0};
  #pragma unroll 4
  for (int k0 = 0; k0 < DMOD; k0 += 32) {
    bf16x8 a  = *(const bf16x8*)(arow  + k0);
    bf16x8 b0 = *(const bf16x8*)(brow0 + k0);
    bf16x8 b1 = *(const bf16x8*)(brow1 + k0);
    acc0 = __builtin_amdgcn_mfma_f32_16x16x32_bf16(a,b0,acc0,0,0,0);
    acc1 = __builtin_amdgcn_mfma_f32_16x16x32_bf16(a,b1,acc1,0,0,0);
  }
  int r0 = c4*4;
  #pragma unroll
  for (int bn=0; bn<2; bn++) {
    f32x4 acc = bn==0?acc0:acc1;
    #pragma unroll
    for (int rr=0; rr<4; rr++)
      out[(size_t)(m0 + wm + r0 + rr)*DMOD + n0 + wn + bn*16 + c16] = acc[rr];
  }
}

// ---------------------------------------------------------------------------
extern "C" void kernel_launch(void* const* d_in, const int* in_sizes, int n_in,
                              void* d_out, int out_size, void* d_ws, size_t ws_size,
                              hipStream_t stream) {
  const float* s   = (const float*)d_in[0];
  const float* z   = (const float*)d_in[1];
  const float* nsw = (const float*)d_in[2];
  const float* nsb = (const float*)d_in[3];
  const float* qw  = (const float*)d_in[4];
  const float* qb  = (const float*)d_in[5];
  const float* kw  = (const float*)d_in[6];
  const float* vw  = (const float*)d_in[7];
  const float* gw  = (const float*)d_in[8];
  const float* znw = (const float*)d_in[9];
  const float* znb = (const float*)d_in[10];
  const float* zw  = (const float*)d_in[11];
  const float* ow  = (const float*)d_in[12];
  float* out = (float*)d_out;

  char* p = (char*)d_ws;
  u16* w_bf    = (u16*)p;  p += (size_t)5*DMOD*DMOD*2;
  u16* sn_bf   = (u16*)p;  p += (size_t)NTOK*DMOD*2;
  u16* q_bf    = (u16*)p;  p += (size_t)NTOK*DMOD*2;
  u16* k_bf    = (u16*)p;  p += (size_t)NTOK*DMOD*2;
  u16* vT_bf   = (u16*)p;  p += (size_t)NTOK*DMOD*2;
  float* g_f   = (float*)p; p += (size_t)NTOK*DMOD*4;
  u16* og_bf   = (u16*)p;  p += (size_t)NTOK*DMOD*2;
  u16* bias_bf = (u16*)p;  p += (size_t)NH*NN*2;

  prep_kernel<<<dim3(10688), dim3(256), 0, stream>>>(
      s, nsw, nsb, qw, kw, vw, gw, ow, z, znw, znb, zw, w_bf, sn_bf, bias_bf);
  qkvg_kernel<<<dim3(768), dim3(256), 0, stream>>>(sn_bf, w_bf, qb, q_bf, k_bf, vT_bf, g_f);
  attn_kernel<<<dim3(768), dim3(256), 0, stream>>>(q_bf, k_bf, vT_bf, bias_bf, g_f, og_bf);
  out_kernel<<<dim3(192), dim3(256), 0, stream>>>(og_bf, w_bf + (size_t)4*DMOD*DMOD, out);
}

// Round 6
// 102.519 us; speedup vs baseline: 1.0798x; 1.0798x over previous
//
#include <hip/hip_runtime.h>
#include <hip/hip_bf16.h>

typedef float f32x4 __attribute__((ext_vector_type(4)));
typedef short bf16x8 __attribute__((ext_vector_type(8)));
typedef unsigned short u16;

#define NTOK 768
#define DMOD 512
#define NH   16
#define DH   32
#define CZd  128
#define NN   (768*768)

static __device__ __forceinline__ u16 f2bf(float f) {
  __hip_bfloat16 h = __float2bfloat16(f);
  return __builtin_bit_cast(u16, h);
}
static __device__ __forceinline__ float bf2f(u16 u) {
  unsigned int x = ((unsigned int)u) << 16;
  return __builtin_bit_cast(float, x);
}

// ---------------------------------------------------------------------------
// K0 "prep": ONE launch; z-stream blocks first, cvt/LN ride along in the tail.
//   blocks [0,9216)      : z path: LN(z) -> @z_w -> bias bf16 [i][h][j]
//   blocks [9216,10496)  : convert 5 weight mats f32 [k][n] -> bf16 [n][k]
//   blocks [10496,10688) : LayerNorm(s) -> bf16, 4 rows per block
// z-read: FULLY COALESCED — per instruction each lane reads 16B at lane*16B
// (1KB contiguous per wave, 4KB per block step). Stats: 5-step shuffle over
// the 32-lane half-wave that owns each row (round-3 verified config).
__global__ __launch_bounds__(256) void prep_kernel(
    const float* __restrict__ s, const float* __restrict__ nsw, const float* __restrict__ nsb,
    const float* __restrict__ qw, const float* __restrict__ kw, const float* __restrict__ vw,
    const float* __restrict__ gw, const float* __restrict__ ow,
    const float* __restrict__ z, const float* __restrict__ znw, const float* __restrict__ znb,
    const float* __restrict__ zwp,
    u16* __restrict__ wbf, u16* __restrict__ snb, u16* __restrict__ biasb) {
  __shared__ char SM[17408];
  int bid = blockIdx.x;
  int t = threadIdx.x;

  if (bid >= 9216) {
    if (bid < 10496) {         // ---- weight convert+transpose ----
      float (*tbuf)[33] = (float(*)[33])SM;
      int wb = bid - 9216;
      int seg = wb / 256;
      int tile = wb % 256;
      int k0 = (tile / 16) * 32;
      int n0 = (tile % 16) * 32;
      const float* src = seg==0?qw: seg==1?kw: seg==2?vw: seg==3?gw: ow;
      u16* out = wbf + (size_t)seg * (DMOD*DMOD);
      int tr  = t / 8;
      int tc4 = (t % 8) * 4;
      float4 v = *(const float4*)(src + (size_t)(k0+tr)*DMOD + n0 + tc4);
      tbuf[tr][tc4+0]=v.x; tbuf[tr][tc4+1]=v.y; tbuf[tr][tc4+2]=v.z; tbuf[tr][tc4+3]=v.w;
      __syncthreads();
      int nr  = t / 8;
      int kc4 = (t % 8) * 4;
      ushort4 o;
      o.x = f2bf(tbuf[kc4+0][nr]);
      o.y = f2bf(tbuf[kc4+1][nr]);
      o.z = f2bf(tbuf[kc4+2][nr]);
      o.w = f2bf(tbuf[kc4+3][nr]);
      *(ushort4*)(out + (size_t)(n0+nr)*DMOD + k0 + kc4) = o;
    } else {                   // ---- LayerNorm(s), 4 rows/block ----
      int i = (bid - 10496)*4 + (t >> 6);
      int lane = t & 63;
      const float* row = s + (size_t)i*DMOD + lane*8;
      float4 a0 = *(const float4*)(row);
      float4 a1 = *(const float4*)(row + 4);
      float sum = a0.x+a0.y+a0.z+a0.w + a1.x+a1.y+a1.z+a1.w;
      float sq  = a0.x*a0.x+a0.y*a0.y+a0.z*a0.z+a0.w*a0.w
                + a1.x*a1.x+a1.y*a1.y+a1.z*a1.z+a1.w*a1.w;
      #pragma unroll
      for (int mk=1; mk<64; mk<<=1) { sum += __shfl_xor(sum,mk); sq += __shfl_xor(sq,mk); }
      float mu  = sum * (1.f/512.f);
      float var = sq  * (1.f/512.f) - mu*mu;
      float rs  = rsqrtf(var + 1e-5f);
      float4 w0 = *(const float4*)(nsw + lane*8);
      float4 w1 = *(const float4*)(nsw + lane*8 + 4);
      float4 b0 = *(const float4*)(nsb + lane*8);
      float4 b1 = *(const float4*)(nsb + lane*8 + 4);
      bf16x8 o;
      o[0]=(short)f2bf((a0.x-mu)*rs*w0.x+b0.x);
      o[1]=(short)f2bf((a0.y-mu)*rs*w0.y+b0.y);
      o[2]=(short)f2bf((a0.z-mu)*rs*w0.z+b0.z);
      o[3]=(short)f2bf((a0.w-mu)*rs*w0.w+b0.w);
      o[4]=(short)f2bf((a1.x-mu)*rs*w1.x+b1.x);
      o[5]=(short)f2bf((a1.y-mu)*rs*w1.y+b1.y);
      o[6]=(short)f2bf((a1.z-mu)*rs*w1.z+b1.z);
      o[7]=(short)f2bf((a1.w-mu)*rs*w1.w+b1.w);
      *(bf16x8*)(snb + (size_t)i*DMOD + lane*8) = o;
    }
    return;
  }

  // ---- z path (blocks [0,9216)) ----
  u16* zt = (u16*)SM;          // 64 rows x pitch 136 bf16
  int i = bid / 12, j0 = (bid % 12) * 64;
  int lane = t & 63, wv = t >> 6;
  int c16 = lane & 15, c4 = lane >> 4;
  int rsub = t >> 5;            // 0..7 : row-in-chunk (half-wave granularity)
  int ch4  = (t & 31) * 4;      // 4 consecutive channels per lane
  const float* ztile = z + ((size_t)i*NTOK + j0)*CZd;
  float4 xv[8];
  #pragma unroll
  for (int it=0; it<8; it++)
    xv[it] = *(const float4*)(ztile + (size_t)(it*8 + rsub)*CZd + ch4);
  // z_w fragments: 32 scalar L2 loads (hidden under the z stream)
  bf16x8 bfr[4];
  #pragma unroll
  for (int ks=0; ks<4; ks++) {
    #pragma unroll
    for (int jj=0; jj<8; jj++)
      bfr[ks][jj] = (short)f2bf(zwp[(ks*32 + c4*8 + jj)*16 + c16]);
  }
  float4 w4 = *(const float4*)(znw + ch4);
  float4 b4 = *(const float4*)(znb + ch4);
  // per-row stats: 5-step shuffle over the 32-lane half-wave owning the row
  float mu8[8], rs8[8];
  #pragma unroll
  for (int it=0; it<8; it++) {
    float4 v = xv[it];
    float sum = v.x+v.y+v.z+v.w;
    float sq  = v.x*v.x+v.y*v.y+v.z*v.z+v.w*v.w;
    #pragma unroll
    for (int mk=1; mk<32; mk<<=1) { sum += __shfl_xor(sum,mk); sq += __shfl_xor(sq,mk); }
    float mu = sum*(1.f/128.f);
    mu8[it] = mu;
    rs8[it] = rsqrtf(sq*(1.f/128.f) - mu*mu + 1e-5f);
  }
  #pragma unroll
  for (int it=0; it<8; it++) {
    float4 v = xv[it];
    float mu = mu8[it], rs = rs8[it];
    ushort4 o;
    o.x = f2bf((v.x-mu)*rs*w4.x + b4.x);
    o.y = f2bf((v.y-mu)*rs*w4.y + b4.y);
    o.z = f2bf((v.z-mu)*rs*w4.z + b4.z);
    o.w = f2bf((v.w-mu)*rs*w4.w + b4.w);
    *(ushort4*)(zt + (it*8 + rsub)*136 + ch4) = o;
  }
  __syncthreads();
  f32x4 acc = {0,0,0,0};
  #pragma unroll
  for (int ks=0; ks<4; ks++) {
    bf16x8 af = *(const bf16x8*)(zt + (wv*16 + c16)*136 + ks*32 + c4*8);
    acc = __builtin_amdgcn_mfma_f32_16x16x32_bf16(af, bfr[ks], acc, 0,0,0);
  }
  int jl = j0 + wv*16 + c4*4;
  u16* bp = biasb + ((size_t)i*NH + c16)*NTOK + jl;
  ushort4 st;
  st.x = f2bf(acc[0]); st.y = f2bf(acc[1]); st.z = f2bf(acc[2]); st.w = f2bf(acc[3]);
  *(ushort4*)bp = st;
}

// ---------------------------------------------------------------------------
// K2: fused Q/K/V/G projections, NO LDS (operands L2-resident), no barriers.
//     grid = 24 (M/32) * 32 (4 mats * 512/64) = 768 blocks of 256.
__global__ __launch_bounds__(256) void qkvg_kernel(
    const u16* __restrict__ sn, const u16* __restrict__ wts, const float* __restrict__ qb,
    u16* __restrict__ qo, u16* __restrict__ ko, u16* __restrict__ vTo, float* __restrict__ go) {
  int bid = blockIdx.x;
  int mb = bid % 24, nb = bid / 24;
  int wsel = nb >> 3, n0 = (nb & 7) * 64, m0 = mb * 32;
  const u16* wt = wts + (size_t)wsel * (DMOD*DMOD);
  int t = threadIdx.x, lane = t & 63, wv = t >> 6;
  int wm = (wv >> 1) * 16, wn = (wv & 1) * 32;
  int c16 = lane & 15, c4 = lane >> 4;
  const u16* arow  = sn + (size_t)(m0 + wm + c16)*DMOD + c4*8;
  const u16* brow0 = wt + (size_t)(n0 + wn + c16)*DMOD + c4*8;
  const u16* brow1 = wt + (size_t)(n0 + wn + 16 + c16)*DMOD + c4*8;
  f32x4 acc0={0,0,0,0}, acc1={0,0,0,0};
  #pragma unroll 4
  for (int k0 = 0; k0 < DMOD; k0 += 32) {
    bf16x8 a  = *(const bf16x8*)(arow  + k0);
    bf16x8 b0 = *(const bf16x8*)(brow0 + k0);
    bf16x8 b1 = *(const bf16x8*)(brow1 + k0);
    acc0 = __builtin_amdgcn_mfma_f32_16x16x32_bf16(a,b0,acc0,0,0,0);
    acc1 = __builtin_amdgcn_mfma_f32_16x16x32_bf16(a,b1,acc1,0,0,0);
  }
  int r0 = c4*4;
  #pragma unroll
  for (int bn=0; bn<2; bn++) {
    f32x4 acc = bn==0?acc0:acc1;
    #pragma unroll
    for (int rr=0; rr<4; rr++) {
      int i = m0 + wm + r0 + rr;
      int n = n0 + wn + bn*16 + c16;
      float val = acc[rr];
      if (wsel == 0)      { val += qb[n]; qo[(size_t)i*DMOD + n] = f2bf(val); }
      else if (wsel == 1) { ko[(size_t)i*DMOD + n] = f2bf(val); }
      else if (wsel == 2) { vTo[(size_t)n*NTOK + i] = f2bf(val); }
      else                { go[(size_t)i*DMOD + n] = 1.f/(1.f + expf(-val)); }
    }
  }
}

// ---------------------------------------------------------------------------
// K3: flash attention. Block = (head, 16-row i-tile), 4 waves split j 4 ways;
//     exact partial-sum combine (no max subtraction). Bias/K/V direct from
//     global (L2-resident). Only LDS: P transpose + combine buffers.
//     grid = 768 blocks of 256.
__global__ __launch_bounds__(256) void attn_kernel(
    const u16* __restrict__ qm, const u16* __restrict__ km, const u16* __restrict__ vTm,
    const u16* __restrict__ bias, const float* __restrict__ gm, u16* __restrict__ og) {
  __shared__ u16 Pt[4][16*72];
  __shared__ float OS[4][16][33];
  __shared__ float LS[4][16];
  int h  = blockIdx.x & 15;
  int i0 = (blockIdx.x >> 4) * 16;
  int t = threadIdx.x, lane = t & 63, wv = t >> 6;
  int c16 = lane & 15, c4 = lane >> 4, r0 = c4 * 4;
  bf16x8 qf = *(const bf16x8*)(qm + (size_t)(i0 + c16)*DMOD + h*DH + c4*8);
  f32x4 o0 = {0,0,0,0}, o1 = {0,0,0,0};
  float ls[4] = {0.f,0.f,0.f,0.f};
  const float scale = 0.17677669529663687f;  // 32^-0.5
  const u16* bbase = bias + ((size_t)i0*NH + h)*NTOK;   // [i][h][j]
  u16* pt = &Pt[wv][0];
  for (int jj = 0; jj < 3; jj++) {
    int j0 = wv*192 + jj*64;
    bf16x8 kf0 = *(const bf16x8*)(km + (size_t)(j0 +  0 + c16)*DMOD + h*DH + c4*8);
    bf16x8 kf1 = *(const bf16x8*)(km + (size_t)(j0 + 16 + c16)*DMOD + h*DH + c4*8);
    bf16x8 kf2 = *(const bf16x8*)(km + (size_t)(j0 + 32 + c16)*DMOD + h*DH + c4*8);
    bf16x8 kf3 = *(const bf16x8*)(km + (size_t)(j0 + 48 + c16)*DMOD + h*DH + c4*8);
    f32x4 zz = {0,0,0,0};
    f32x4 s0 = __builtin_amdgcn_mfma_f32_16x16x32_bf16(qf,kf0,zz,0,0,0);
    f32x4 s1 = __builtin_amdgcn_mfma_f32_16x16x32_bf16(qf,kf1,zz,0,0,0);
    f32x4 s2 = __builtin_amdgcn_mfma_f32_16x16x32_bf16(qf,kf2,zz,0,0,0);
    f32x4 s3 = __builtin_amdgcn_mfma_f32_16x16x32_bf16(qf,kf3,zz,0,0,0);
    #pragma unroll
    for (int rr=0; rr<4; rr++) {
      const u16* bp = bbase + (size_t)(r0+rr)*(NH*NTOK) + j0 + c16;
      int row = (r0 + rr) * 72;
      float p0 = __expf(s0[rr]*scale + bf2f(bp[ 0]));
      float p1 = __expf(s1[rr]*scale + bf2f(bp[16]));
      float p2 = __expf(s2[rr]*scale + bf2f(bp[32]));
      float p3 = __expf(s3[rr]*scale + bf2f(bp[48]));
      ls[rr] += p0 + p1 + p2 + p3;
      pt[row + 0*16 + c16] = f2bf(p0);
      pt[row + 1*16 + c16] = f2bf(p1);
      pt[row + 2*16 + c16] = f2bf(p2);
      pt[row + 3*16 + c16] = f2bf(p3);
    }
    #pragma unroll
    for (int ks=0; ks<2; ks++) {
      bf16x8 pf = *(const bf16x8*)(pt + c16*72 + ks*32 + c4*8);
      bf16x8 v0 = *(const bf16x8*)(vTm + (size_t)(h*DH + c16)*NTOK      + j0 + ks*32 + c4*8);
      bf16x8 v1 = *(const bf16x8*)(vTm + (size_t)(h*DH + 16 + c16)*NTOK + j0 + ks*32 + c4*8);
      o0 = __builtin_amdgcn_mfma_f32_16x16x32_bf16(pf, v0, o0, 0,0,0);
      o1 = __builtin_amdgcn_mfma_f32_16x16x32_bf16(pf, v1, o1, 0,0,0);
    }
  }
  #pragma unroll
  for (int rr=0; rr<4; rr++) {
    float l = ls[rr];
    l += __shfl_xor(l,1); l += __shfl_xor(l,2); l += __shfl_xor(l,4); l += __shfl_xor(l,8);
    OS[wv][r0+rr][c16]      = o0[rr];
    OS[wv][r0+rr][16 + c16] = o1[rr];
    if (c16 == 0) LS[wv][r0+rr] = l;
  }
  __syncthreads();
  #pragma unroll
  for (int u=0; u<2; u++) {
    int idx = t + u*256;
    int row = idx >> 5, d = idx & 31;
    float osum = OS[0][row][d] + OS[1][row][d] + OS[2][row][d] + OS[3][row][d];
    float lsum = LS[0][row] + LS[1][row] + LS[2][row] + LS[3][row];
    int i = i0 + row;
    float g = gm[(size_t)i*DMOD + h*DH + d];
    og[(size_t)i*DMOD + h*DH + d] = f2bf(osum/lsum*g);
  }
}

// ---------------------------------------------------------------------------
// K4: out = og @ o_w, NO LDS (both operands L2-resident), 32x64 tiles.
//     grid = 24*8 = 192 blocks of 256.
__global__ __launch_bounds__(256) void out_kernel(
    const u16* __restrict__ og, const u16* __restrict__ owT, float* __restrict__ out) {
  int bid = blockIdx.x;
  int mb = bid % 24, nb = bid / 24;
  int m0 = mb*32, n0 = nb*64;
  int t = threadIdx.x, lane = t & 63, wv = t >> 6;
  int wm = (wv >> 1) * 16, wn = (wv & 1) * 32;
  int c16 = lane & 15, c4 = lane >> 4;
  const u16* arow  = og  + (size_t)(m0 + wm + c16)*DMOD + c4*8;
  const u16* brow0 = owT + (size_t)(n0 + wn + c16)*DMOD + c4*8;
  const u16* brow1 = owT + (size_t)(n0 + wn + 16 + c16)*DMOD + c4*8;
  f32x4 acc0={0,0,0,0}, acc1={0,0,0,0};
  #pragma unroll 4
  for (int k0 = 0; k0 < DMOD; k0 += 32) {
    bf16x8 a  = *(const bf16x8*)(arow  + k0);
    bf16x8 b0 = *(const bf16x8*)(brow0 + k0);
    bf16x8 b1 = *(const bf16x8*)(brow1 + k0);
    acc0 = __builtin_amdgcn_mfma_f32_16x16x32_bf16(a,b0,acc0,0,0,0);
    acc1 = __builtin_amdgcn_mfma_f32_16x16x32_bf16(a,b1,acc1,0,0,0);
  }
  int r0 = c4*4;
  #pragma unroll
  for (int bn=0; bn<2; bn++) {
    f32x4 acc = bn==0?acc0:acc1;
    #pragma unroll
    for (int rr=0; rr<4; rr++)
      out[(size_t)(m0 + wm + r0 + rr)*DMOD + n0 + wn + bn*16 + c16] = acc[rr];
  }
}

// ---------------------------------------------------------------------------
extern "C" void kernel_launch(void* const* d_in, const int* in_sizes, int n_in,
                              void* d_out, int out_size, void* d_ws, size_t ws_size,
                              hipStream_t stream) {
  const float* s   = (const float*)d_in[0];
  const float* z   = (const float*)d_in[1];
  const float* nsw = (const float*)d_in[2];
  const float* nsb = (const float*)d_in[3];
  const float* qw  = (const float*)d_in[4];
  const float* qb  = (const float*)d_in[5];
  const float* kw  = (const float*)d_in[6];
  const float* vw  = (const float*)d_in[7];
  const float* gw  = (const float*)d_in[8];
  const float* znw = (const float*)d_in[9];
  const float* znb = (const float*)d_in[10];
  const float* zw  = (const float*)d_in[11];
  const float* ow  = (const float*)d_in[12];
  float* out = (float*)d_out;

  char* p = (char*)d_ws;
  u16* w_bf    = (u16*)p;  p += (size_t)5*DMOD*DMOD*2;
  u16* sn_bf   = (u16*)p;  p += (size_t)NTOK*DMOD*2;
  u16* q_bf    = (u16*)p;  p += (size_t)NTOK*DMOD*2;
  u16* k_bf    = (u16*)p;  p += (size_t)NTOK*DMOD*2;
  u16* vT_bf   = (u16*)p;  p += (size_t)NTOK*DMOD*2;
  float* g_f   = (float*)p; p += (size_t)NTOK*DMOD*4;
  u16* og_bf   = (u16*)p;  p += (size_t)NTOK*DMOD*2;
  u16* bias_bf = (u16*)p;  p += (size_t)NH*NN*2;

  prep_kernel<<<dim3(10688), dim3(256), 0, stream>>>(
      s, nsw, nsb, qw, kw, vw, gw, ow, z, znw, znb, zw, w_bf, sn_bf, bias_bf);
  qkvg_kernel<<<dim3(768), dim3(256), 0, stream>>>(sn_bf, w_bf, qb, q_bf, k_bf, vT_bf, g_f);
  attn_kernel<<<dim3(768), dim3(256), 0, stream>>>(q_bf, k_bf, vT_bf, bias_bf, g_f, og_bf);
  out_kernel<<<dim3(192), dim3(256), 0, stream>>>(og_bf, w_bf + (size_t)4*DMOD*DMOD, out);
}